// Round 9
// baseline (522.015 us; speedup 1.0000x reference)
//
#include <hip/hip_runtime.h>

typedef short  short8   __attribute__((ext_vector_type(8)));
typedef float  floatx16 __attribute__((ext_vector_type(16)));

#define HID  128
#define LDM  280   // msg row stride (272 data + 8 pad), 16B-aligned rows
#define LDZ  136   // z1 row stride
#define NK1  17    // 272 = 17*16 exactly — no K padding needed
#define NK2  8     // 128/16

__device__ __forceinline__ float fast_silu(float v) {
    return __fdividef(v, 1.0f + __expf(-v));
}
// scalar f32 -> bf16 RNE (bit-twiddle; ROCm 7.2 here lacks __floats2bfloat162_rn)
__device__ __forceinline__ unsigned short f2bf(float f) {
    union { float f; unsigned int u; } v; v.f = f;
    unsigned int r = v.u + 0x7FFFu + ((v.u >> 16) & 1u);
    return (unsigned short)(r >> 16);
}
// packed pair via two scalar casts
__device__ __forceinline__ unsigned int pk2bf(float a, float b) {
    return (unsigned int)f2bf(a) | ((unsigned int)f2bf(b) << 16);
}

// ---- fused prep: W1T/W2T fragment-linear bf16 + h cast to bf16 ----
// fragment-linear: chunk ((nt*NKS + ks)*64 + lane) of 8 bf16;
// lane supplies n = 32*nt + (lane&31), k = 16*ks + 8*(lane>>5) + j.
__global__ void prep_all(const float* __restrict__ W1, const float* __restrict__ W2,
                         const float* __restrict__ h,
                         unsigned short* __restrict__ w1t, unsigned short* __restrict__ w2t,
                         unsigned short* __restrict__ hb, int nh8)
{
    const int NW1 = 4 * NK1 * 64;   // 4352
    const int NW2 = 4 * NK2 * 64;   // 2048
    const int tot = NW1 + NW2 + nh8;
    union { unsigned short s[8]; uint4 v; } o;
    for (int id = blockIdx.x * blockDim.x + threadIdx.x; id < tot;
         id += gridDim.x * blockDim.x) {
        if (id < NW1) {
            const int nt   = id / (NK1 * 64);
            const int rem  = id % (NK1 * 64);
            const int ks   = rem / 64;
            const int lane = rem % 64;
            const int n  = 32 * nt + (lane & 31);
            const int kb = 16 * ks + 8 * (lane >> 5);
            #pragma unroll
            for (int j = 0; j < 8; ++j) o.s[j] = f2bf(W1[(size_t)(kb + j) * HID + n]);
            *(uint4*)(w1t + (size_t)id * 8) = o.v;
        } else if (id < NW1 + NW2) {
            const int id2  = id - NW1;
            const int nt   = id2 / (NK2 * 64);
            const int rem  = id2 % (NK2 * 64);
            const int ks   = rem / 64;
            const int lane = rem % 64;
            const int n  = 32 * nt + (lane & 31);
            const int kb = 16 * ks + 8 * (lane >> 5);
            #pragma unroll
            for (int j = 0; j < 8; ++j) o.s[j] = f2bf(W2[(size_t)(kb + j) * HID + n]);
            *(uint4*)(w2t + (size_t)id2 * 8) = o.v;
        } else {
            const int i = id - NW1 - NW2;            // 8 floats -> 8 bf16
            const float4 va = ((const float4*)h)[2 * i];
            const float4 vb = ((const float4*)h)[2 * i + 1];
            uint4 w;
            w.x = pk2bf(va.x, va.y); w.y = pk2bf(va.z, va.w);
            w.z = pk2bf(vb.x, vb.y); w.w = pk2bf(vb.z, vb.w);
            ((uint4*)hb)[i] = w;
        }
    }
}

// ---- main: persistent blocks, 64 edges/iter, 8 waves = 4 n-tiles x 2 e-tiles ----
__global__ __launch_bounds__(512, 4) void egnn_mfma_kernel(
    const unsigned short* __restrict__ hb,    // [N][128] bf16
    const int* __restrict__ eidx,             // [2][E]
    const float* __restrict__ edge_attr,      // [E][16] fp32 (cast in-kernel)
    const float* __restrict__ coord_diff,     // [E][3]
    const unsigned short* __restrict__ w1t,   // fragment-linear
    const unsigned short* __restrict__ w2t,
    const float* __restrict__ b1,
    const float* __restrict__ b2,
    const float* __restrict__ W3,
    float* __restrict__ agg,
    int E, int niter)
{
    __shared__ unsigned short s_msg[64][LDM];  // 35,840 B
    __shared__ unsigned short s_z1[64][LDZ];   // 17,408 B
    __shared__ float s_z3[64];
    __shared__ int   s_row[64];

    const int t    = threadIdx.x;
    const int lane = t & 63;
    const int w    = t >> 6;        // 0..7
    const int nt   = w & 3;         // n-tile
    const int et   = w >> 2;        // e-tile (0,1)
    const int c31  = lane & 31;
    const int hi   = lane >> 5;

    // bias/W3 fragments for this wave's n-tile: n = 32nt + (r&3) + 8(r>>2) + 4hi
    float b1f[16], b2f[16], w3f[16];
    #pragma unroll
    for (int r = 0; r < 16; ++r) {
        const int n = 32 * nt + (r & 3) + 8 * (r >> 2) + 4 * hi;
        b1f[r] = b1[n]; b2f[r] = b2[n]; w3f[r] = W3[n];
    }

    for (int it = blockIdx.x; it < niter; it += gridDim.x) {
        const int ebase = it * 64;

        // ---------- gather: 8 threads per edge ----------
        {
            const int e = t >> 3, s = t & 7;
            const int g  = ebase + e;
            const int gc = (g < E) ? g : (E - 1);
            const int row = eidx[gc];
            const int col = eidx[(size_t)E + gc];
            if (s == 0) s_row[e] = row;
            if (t < 64) s_z3[t] = 0.0f;
            const uint4* hr = (const uint4*)(hb + (size_t)row * HID);
            const uint4* hc = (const uint4*)(hb + (size_t)col * HID);
            *(uint4*)&s_msg[e][s * 8]             = hr[s];
            *(uint4*)&s_msg[e][(s + 8) * 8]       = hr[s + 8];
            *(uint4*)&s_msg[e][HID + s * 8]       = hc[s];
            *(uint4*)&s_msg[e][HID + (s + 8) * 8] = hc[s + 8];
            if (s < 4) {   // edge_attr fp32 -> bf16 in-flight
                const float4 ea = ((const float4*)(edge_attr + (size_t)gc * 16))[s];
                *(uint2*)&s_msg[e][256 + s * 4] =
                    make_uint2(pk2bf(ea.x, ea.y), pk2bf(ea.z, ea.w));
            }
        }
        __syncthreads();

        // ---------- GEMM1: z1 = silu(msg @ W1 + b1), D[n][e] ----------
        floatx16 acc = {};
        #pragma unroll
        for (int ks = 0; ks < NK1; ++ks) {
            const short8 wf = *(const short8*)(w1t + ((size_t)(nt * NK1 + ks) * 64 + lane) * 8);
            const short8 af = *(const short8*)&s_msg[32 * et + c31][16 * ks + 8 * hi];
            acc = __builtin_amdgcn_mfma_f32_32x32x16_bf16(wf, af, acc, 0, 0, 0);
        }
        #pragma unroll
        for (int q = 0; q < 4; ++q) {
            const float f0 = fast_silu(acc[4*q+0] + b1f[4*q+0]);
            const float f1 = fast_silu(acc[4*q+1] + b1f[4*q+1]);
            const float f2 = fast_silu(acc[4*q+2] + b1f[4*q+2]);
            const float f3 = fast_silu(acc[4*q+3] + b1f[4*q+3]);
            *(uint2*)&s_z1[32 * et + c31][32 * nt + 8 * q + 4 * hi] =
                make_uint2(pk2bf(f0, f1), pk2bf(f2, f3));
        }
        __syncthreads();

        // ---------- GEMM2 + W3 dot ----------
        floatx16 g2 = {};
        #pragma unroll
        for (int ks = 0; ks < NK2; ++ks) {
            const short8 wf = *(const short8*)(w2t + ((size_t)(nt * NK2 + ks) * 64 + lane) * 8);
            const short8 af = *(const short8*)&s_z1[32 * et + c31][16 * ks + 8 * hi];
            g2 = __builtin_amdgcn_mfma_f32_32x32x16_bf16(wf, af, g2, 0, 0, 0);
        }
        float p = 0.0f;
        #pragma unroll
        for (int r = 0; r < 16; ++r) p += fast_silu(g2[r] + b2f[r]) * w3f[r];
        p += __shfl_xor(p, 32, 64);
        if (hi == 0) atomicAdd(&s_z3[32 * et + c31], p);
        __syncthreads();

        // ---------- epilogue: tanh, scale, scatter (wave 0) ----------
        if (t < 64) {
            const int g = ebase + t;
            if (g < E) {
                const float sc = tanhf(s_z3[t]) * 15.0f;   // COORDS_RANGE
                const int row = s_row[t];
                const float* cd = coord_diff + (size_t)g * 3;
                atomicAdd(&agg[row * 3 + 0], cd[0] * sc);
                atomicAdd(&agg[row * 3 + 1], cd[1] * sc);
                atomicAdd(&agg[row * 3 + 2], cd[2] * sc);
            }
        }
        __syncthreads();   // protect s_msg/s_row/s_z3 before next iter
    }
}

__global__ void finalize_kernel(const float* __restrict__ x,
                                const float* __restrict__ flags,
                                float* __restrict__ out, int n3)
{
    const int i = blockIdx.x * blockDim.x + threadIdx.x;
    if (i < n3) {
        const int n = i / 3;
        out[i] = (out[i] + x[i]) * flags[n];
    }
}

extern "C" void kernel_launch(void* const* d_in, const int* in_sizes, int n_in,
                              void* d_out, int out_size, void* d_ws, size_t ws_size,
                              hipStream_t stream)
{
    const float* h          = (const float*)d_in[0];
    const float* x          = (const float*)d_in[1];
    const int*   eix        = (const int*)d_in[2];   // int64 in reference -> int32 here
    const float* edge_attr  = (const float*)d_in[3];
    const float* coord_diff = (const float*)d_in[4];
    const float* flags      = (const float*)d_in[5];
    // d_in[6] edge_mask: computed-but-unused in reference; ignored.
    const float* W1 = (const float*)d_in[7];
    const float* b1 = (const float*)d_in[8];
    const float* W2 = (const float*)d_in[9];
    const float* b2 = (const float*)d_in[10];
    const float* W3 = (const float*)d_in[11];
    float* out = (float*)d_out;

    const int N3 = in_sizes[1];       // N_NODES * 3
    const int E  = in_sizes[4] / 3;
    const int nh = in_sizes[0];       // N_NODES * 128

    // d_ws layout (bytes): [0, 69632) W1T | [69632, 102400) W2T | [102400, ...) h_bf16
    unsigned short* w1t = (unsigned short*)d_ws;
    unsigned short* w2t = w1t + 4 * NK1 * 64 * 8;     // short offset 34816
    unsigned short* hb  = (unsigned short*)((char*)d_ws + 102400);

    (void)hipMemsetAsync(out, 0, (size_t)N3 * sizeof(float), stream);
    prep_all<<<1024, 256, 0, stream>>>(W1, W2, h, w1t, w2t, hb, nh >> 3);

    const int niter = (E + 63) / 64;
    egnn_mfma_kernel<<<512, 512, 0, stream>>>(hb, eix, edge_attr, coord_diff,
                                              w1t, w2t, b1, b2, W3, out, E, niter);
    finalize_kernel<<<(N3 + 255) / 256, 256, 0, stream>>>(x, flags, out, N3);
}